// Round 3
// baseline (14031.033 us; speedup 1.0000x reference)
//
#include <hip/hip_runtime.h>
#include <math.h>

#define T      512
#define NBATCH 512
#define IN_DIM 64
#define H      100
#define HP     104   // padded h rows (float4-aligned)
#define KP     100   // uniform (padded) contraction length, multiple of 4

// tanh(a) = 1 - 2/(exp(2a)+1)  -- overflow-safe at both ends.
__device__ __forceinline__ float fast_tanh(float a) {
    float e = __expf(2.0f * a);
    return 1.0f - 2.0f / (e + 1.0f);
}

// ---- compile-time-unrolled weight init: all w[] indices are template
// constants, so SROA scalarizes the allocas into VGPRs (runtime-indexed
// loops blocked promotion in R1/R2 -> scratch spill, 21 GB HBM refetch).
template<int K, int N>
struct WInit {
    __device__ __forceinline__ static void run(float* w, const float* __restrict__ W,
                                               int jc, int KA) {
        float v = W[((K < 64) ? K : 0) * H + jc];        // addr clamped vs W1x OOB
        float v2 = (K >= 64) ? W[K * H + jc] : v;        // full range when KA==100
        w[K] = (K < KA) ? ((K < 64) ? v : v2) : 0.f;
        WInit<K + 1, N>::run(w, W, jc, KA);
    }
};
template<int N>
struct WInit<N, N> {
    __device__ __forceinline__ static void run(float*, const float*, int, int) {}
};

// ---- compile-time-unrolled 4-chain dot step over float4 chunks ----
template<int C, int N>
struct DotLoop {
    __device__ __forceinline__ static void run(const float4* __restrict__ A,
                                               const float* __restrict__ w,
                                               float& a0, float& a1, float& a2, float& a3) {
        float4 v = A[C];
        a0 = fmaf(v.x, w[4 * C + 0], a0);
        a1 = fmaf(v.y, w[4 * C + 1], a1);
        a2 = fmaf(v.z, w[4 * C + 2], a2);
        a3 = fmaf(v.w, w[4 * C + 3], a3);
        DotLoop<C + 1, N>::run(A, w, a0, a1, a2, a3);
    }
};
template<int N>
struct DotLoop<N, N> {
    __device__ __forceinline__ static void run(const float4*, const float*,
                                               float&, float&, float&, float&) {}
};

__device__ __forceinline__ float dot200(const float4* __restrict__ A,
                                        const float4* __restrict__ Bv,
                                        const float* __restrict__ wA,
                                        const float* __restrict__ wB, float bj) {
    float a0 = bj, a1 = 0.f, a2 = 0.f, a3 = 0.f;
    DotLoop<0, KP / 4>::run(A, wA, a0, a1, a2, a3);
    DotLoop<0, KP / 4>::run(Bv, wB, a0, a1, a2, a3);
    return fast_tanh((a0 + a1) + (a2 + a3));
}

// One block per batch element. Threads 0..127: layer-1 neurons (j=tid),
// threads 128..255: layer-2 neurons (j=tid-128), pipelined one timestep
// behind layer 1. Uniform code path: L1's x-contribution padded 64->100
// with zeros so every thread runs the same 200-FMA dot; only base
// pointers differ (per-wave uniform). Weights in VGPRs.
__global__ __launch_bounds__(256, 2)
void drnn_kernel(const float* __restrict__ x,
                 const float* __restrict__ W1x, const float* __restrict__ W1h,
                 const float* __restrict__ b1,
                 const float* __restrict__ W2x, const float* __restrict__ W2h,
                 const float* __restrict__ b2,
                 const float* __restrict__ Wo,  const float* __restrict__ bo,
                 float* __restrict__ out)
{
    __shared__ __align__(16) float h1buf[2][HP];
    __shared__ __align__(16) float h2buf[2][HP];
    __shared__ __align__(16) float xbuf[2][HP];   // [64..99] stay 0 forever

    const int tid = threadIdx.x;
    const int b   = blockIdx.x;
    const float* __restrict__ xrow = x + (size_t)b * T * IN_DIM;

    if (tid < HP) {
        h1buf[0][tid] = 0.f; h1buf[1][tid] = 0.f;
        h2buf[0][tid] = 0.f; h2buf[1][tid] = 0.f;
        if (tid >= IN_DIM) { xbuf[0][tid] = 0.f; xbuf[1][tid] = 0.f; }
    }
    if (tid < IN_DIM) xbuf[0][tid] = xrow[tid];   // x(0)

    const bool isL1 = (tid < 128);
    const int  j    = isL1 ? tid : (tid - 128);
    const bool act  = (j < H);
    const int  jc   = act ? j : (H - 1);          // clamp for weight loads

    const float* __restrict__ WA = isL1 ? W1x : W2x;
    const float* __restrict__ WB = isL1 ? W1h : W2h;
    const int KA = isL1 ? IN_DIM : H;
    const float bj = isL1 ? b1[jc] : b2[jc];

    float wA[KP], wB[KP];
    WInit<0, KP>::run(wA, WA, jc, KA);
    WInit<0, KP>::run(wB, WB, jc, H);

    // even/odd-iteration LDS pointers (selected once; per-wave uniform)
    const float4* __restrict__ inA_e = (const float4*)(isL1 ? xbuf[0] : h1buf[1]);
    const float4* __restrict__ inB_e = (const float4*)(isL1 ? h1buf[1] : h2buf[0]);
    float*                     wr_e  = isL1 ? &h1buf[0][j] : &h2buf[1][j];
    const float4* __restrict__ inA_o = (const float4*)(isL1 ? xbuf[1] : h1buf[0]);
    const float4* __restrict__ inB_o = (const float4*)(isL1 ? h1buf[0] : h2buf[1]);
    float*                     wr_o  = isL1 ? &h1buf[1][j] : &h2buf[0][j];

    // x register pipeline (wave 0)
    float xr0 = 0.f, xr1 = 0.f;
    if (tid < 64) {
        xr0 = xrow[1 * IN_DIM + tid];   // x(1)
        xr1 = xrow[2 * IN_DIM + tid];   // x(2)
    }

    __syncthreads();

    // Iter i: L1 computes h1(i); L2 computes h2(i-1).
    #pragma unroll 1
    for (int i = 0; i < T; i += 2) {
        // ---- even body ----
        {
            float hv = dot200(inA_e, inB_e, wA, wB, bj);
            if (act && (isL1 | (i > 0))) *wr_e = hv;   // skip bogus h2(-1)
            if (tid < 64) {
                xbuf[1][tid] = xr0;                    // x(i+1)
                xr0 = xr1;
                if (i + 3 < T) xr1 = xrow[(size_t)(i + 3) * IN_DIM + tid];
            }
        }
        __syncthreads();
        // ---- odd body (iter i+1) ----
        {
            float hv = dot200(inA_o, inB_o, wA, wB, bj);
            if (act) *wr_o = hv;
            if (tid < 64) {
                xbuf[0][tid] = xr0;                    // x(i+2)
                xr0 = xr1;
                if (i + 4 < T) xr1 = xrow[(size_t)(i + 4) * IN_DIM + tid];
            }
        }
        __syncthreads();
    }

    // tail iter i = T (even parity): only L2 computes h2(T-1)
    if (!isL1) {
        float hv = dot200(inA_e, inB_e, wA, wB, bj);   // h1buf[1]=h1(T-1), h2buf[0]=h2(T-2)
        if (act) *wr_e = hv;                            // -> h2buf[1]
    }
    __syncthreads();

    // epilogue: h1(T-1) in h1buf[1], h2(T-1) in h2buf[1]
    if (isL1 && act)
        out[NBATCH + (size_t)b * H + j] = h1buf[1][j];
    if (!isL1 && act)
        out[NBATCH + (size_t)NBATCH * H + (size_t)b * H + j] = h2buf[1][j];

    // out[b] = h2_T . Wo + bo  (wave-0 shuffle reduction)
    if (tid < 64) {
        float v = h2buf[1][tid] * Wo[tid];
        if (tid + 64 < H) v += h2buf[1][tid + 64] * Wo[tid + 64];
        #pragma unroll
        for (int off = 32; off >= 1; off >>= 1) v += __shfl_down(v, off);
        if (tid == 0) out[b] = v + bo[0];
    }
}

extern "C" void kernel_launch(void* const* d_in, const int* in_sizes, int n_in,
                              void* d_out, int out_size, void* d_ws, size_t ws_size,
                              hipStream_t stream) {
    const float* x   = (const float*)d_in[0];
    const float* W1x = (const float*)d_in[1];
    const float* W1h = (const float*)d_in[2];
    const float* b1  = (const float*)d_in[3];
    const float* W2x = (const float*)d_in[4];
    const float* W2h = (const float*)d_in[5];
    const float* b2  = (const float*)d_in[6];
    const float* Wo  = (const float*)d_in[7];
    const float* bo  = (const float*)d_in[8];
    float* out = (float*)d_out;

    drnn_kernel<<<NBATCH, 256, 0, stream>>>(x, W1x, W1h, b1, W2x, W2h, b2,
                                            Wo, bo, out);
}

// Round 4
// 743.253 us; speedup vs baseline: 18.8779x; 18.8779x over previous
//
#include <hip/hip_runtime.h>
#include <math.h>

#define T      512
#define NBATCH 512
#define IN_DIM 64
#define H      100
#define HP     104   // padded h rows: 26 float4 chunks; [100..103] stay 0

// tanh(a) = 1 - 2/(exp(2a)+1)  -- overflow-safe at both ends.
__device__ __forceinline__ float fast_tanh(float a) {
    float e = __expf(2.0f * a);
    return 1.0f - 2.0f / (e + 1.0f);
}

// ---------------------------------------------------------------------------
// Weights live in 26 NAMED float4 variables per thread (wa0..wa12, wb0..wb12)
// -> guaranteed SSA / VGPR-resident. (R1-R3: local arrays wA[100]/wB[100]
// were never promoted by SROA -> scratch spill -> 21 GB/launch HBM refetch.)
//
// Block = 512 threads. tid 0..255: layer-1, tid 256..511: layer-2 (pipelined
// one timestep behind). Neuron j = (tid&255)>>1, half = tid&1. Each half owns
// the even (half=0) or odd (half=1) float4 chunks of the neuron's 200-long
// contraction: A-part = x (L1, padded 64->100) or h1 (L2); B-part = own
// layer's recurrent h. Partial dots combined with one __shfl_xor(s,1).
// ---------------------------------------------------------------------------

#define ALLC(X) X(0) X(1) X(2) X(3) X(4) X(5) X(6) X(7) X(8) X(9) X(10) X(11) X(12)

// load one float4 weight chunk g (elements 4g..4g+3) of column jc, rows >= kv -> 0
#define WLOAD1(reg, Wp, g, kv) do {                                   \
    const int k0_ = 4 * (g);                                          \
    reg.x = ((k0_ + 0) < (kv)) ? (Wp)[(k0_ + 0) * H + jc] : 0.f;      \
    reg.y = ((k0_ + 1) < (kv)) ? (Wp)[(k0_ + 1) * H + jc] : 0.f;      \
    reg.z = ((k0_ + 2) < (kv)) ? (Wp)[(k0_ + 2) * H + jc] : 0.f;      \
    reg.w = ((k0_ + 3) < (kv)) ? (Wp)[(k0_ + 3) * H + jc] : 0.f;      \
} while (0)

#define WLOAD(c) WLOAD1(wa##c, WpA, 2*(c)+half, kvA); \
                 WLOAD1(wb##c, WpB, 2*(c)+half, kvB);

// one dot step: chunk 2c+half from each input, 8 accumulator chains
#define STEP(c) {                                                     \
    float4 va_ = (pA_)[2*(c) + half];                                 \
    r0 = fmaf(va_.x, wa##c.x, r0); r1 = fmaf(va_.y, wa##c.y, r1);     \
    r2 = fmaf(va_.z, wa##c.z, r2); r3 = fmaf(va_.w, wa##c.w, r3);     \
    float4 vb_ = (pB_)[2*(c) + half];                                 \
    q0 = fmaf(vb_.x, wb##c.x, q0); q1 = fmaf(vb_.y, wb##c.y, q1);     \
    q2 = fmaf(vb_.z, wb##c.z, q2); q3 = fmaf(vb_.w, wb##c.w, q3); }

#define DOT(pA, pB, hv) {                                             \
    const float4* pA_ = (pA); const float4* pB_ = (pB);               \
    float r0 = 0.f, r1 = 0.f, r2 = 0.f, r3 = 0.f;                     \
    float q0 = 0.f, q1 = 0.f, q2 = 0.f, q3 = 0.f;                     \
    ALLC(STEP)                                                        \
    float s_ = ((r0 + r1) + (r2 + r3)) + ((q0 + q1) + (q2 + q3));     \
    s_ += __shfl_xor(s_, 1);                                          \
    hv = fast_tanh(s_ + bj); }

__global__ __launch_bounds__(512, 2)
void drnn_kernel(const float* __restrict__ x,
                 const float* __restrict__ W1x, const float* __restrict__ W1h,
                 const float* __restrict__ b1,
                 const float* __restrict__ W2x, const float* __restrict__ W2h,
                 const float* __restrict__ b2,
                 const float* __restrict__ Wo,  const float* __restrict__ bo,
                 float* __restrict__ out)
{
    __shared__ __align__(16) float h1buf[2][HP];
    __shared__ __align__(16) float h2buf[2][HP];
    __shared__ __align__(16) float xbuf[2][HP];   // [64..103] stay 0 forever

    const int tid = threadIdx.x;
    const int b   = blockIdx.x;
    const float* __restrict__ xrow = x + (size_t)b * T * IN_DIM;

    // ---- zero-init LDS state ----
    if (tid < HP) {
        h1buf[0][tid] = 0.f; h1buf[1][tid] = 0.f;
        h2buf[0][tid] = 0.f; h2buf[1][tid] = 0.f;
        xbuf[0][tid]  = 0.f; xbuf[1][tid]  = 0.f;
    }
    if (tid < IN_DIM) xbuf[0][tid] = xrow[tid];   // x(0)

    const bool isL1 = (tid < 256);
    const int  j    = (tid & 255) >> 1;           // neuron slot 0..127
    const int  half = tid & 1;                    // even/odd chunk owner
    const bool act  = (j < H);
    const int  jc   = act ? j : (H - 1);          // clamp for weight loads
    const bool wr_ok = act && (half == 0);

    const float* __restrict__ WpA = isL1 ? W1x : W2x;
    const float* __restrict__ WpB = isL1 ? W1h : W2h;
    const int kvA = isL1 ? IN_DIM : H;
    const int kvB = H;
    const float bj = (isL1 ? b1 : b2)[jc];

    // ---- 26 named float4 weight registers ----
    float4 wa0, wa1, wa2, wa3, wa4, wa5, wa6, wa7, wa8, wa9, wa10, wa11, wa12;
    float4 wb0, wb1, wb2, wb3, wb4, wb5, wb6, wb7, wb8, wb9, wb10, wb11, wb12;
    ALLC(WLOAD)

    // ---- even/odd-iteration LDS pointers (wave-uniform) ----
    const float4* pA_e = (const float4*)(isL1 ? xbuf[0] : h1buf[1]);
    const float4* pB_e = (const float4*)(isL1 ? h1buf[1] : h2buf[0]);
    float*        wr_e = isL1 ? &h1buf[0][j] : &h2buf[1][j];
    const float4* pA_o = (const float4*)(isL1 ? xbuf[1] : h1buf[0]);
    const float4* pB_o = (const float4*)(isL1 ? h1buf[0] : h2buf[1]);
    float*        wr_o = isL1 ? &h1buf[1][j] : &h2buf[0][j];

    // ---- x register pipeline (wave 0) ----
    float xr0 = 0.f, xr1 = 0.f;
    if (tid < 64) {
        xr0 = xrow[1 * IN_DIM + tid];   // x(1)
        xr1 = xrow[2 * IN_DIM + tid];   // x(2)
    }

    __syncthreads();

    // Iter i: L1 computes h1(i); L2 computes h2(i-1).
    #pragma unroll 1
    for (int i = 0; i < T; i += 2) {
        // ---- even body ----
        {
            float hv;
            DOT(pA_e, pB_e, hv)
            if (wr_ok && (isL1 | (i > 0))) *wr_e = hv;   // skip bogus h2(-1)
            if (tid < 64) {
                xbuf[1][tid] = xr0;                      // x(i+1)
                xr0 = xr1;
                if (i + 3 < T) xr1 = xrow[(size_t)(i + 3) * IN_DIM + tid];
            }
        }
        __syncthreads();
        // ---- odd body (iter i+1) ----
        {
            float hv;
            DOT(pA_o, pB_o, hv)
            if (wr_ok) *wr_o = hv;
            if (tid < 64) {
                xbuf[0][tid] = xr0;                      // x(i+2)
                xr0 = xr1;
                if (i + 4 < T) xr1 = xrow[(size_t)(i + 4) * IN_DIM + tid];
            }
        }
        __syncthreads();
    }

    // ---- tail iter i = T (even parity): only L2 computes h2(T-1) ----
    if (!isL1) {
        float hv;
        DOT(pA_e, pB_e, hv)   // h1buf[1]=h1(T-1), h2buf[0]=h2(T-2)
        if (wr_ok) *wr_e = hv;                           // -> h2buf[1]
    }
    __syncthreads();

    // ---- epilogue: h1(T-1) in h1buf[1], h2(T-1) in h2buf[1] ----
    if (isL1 && wr_ok)
        out[NBATCH + (size_t)b * H + j] = h1buf[1][j];
    if (!isL1 && wr_ok)
        out[NBATCH + (size_t)NBATCH * H + (size_t)b * H + j] = h2buf[1][j];

    // out[b] = h2_T . Wo + bo  (wave-0 shuffle reduction)
    if (tid < 64) {
        float v = h2buf[1][tid] * Wo[tid];
        if (tid + 64 < H) v += h2buf[1][tid + 64] * Wo[tid + 64];
        #pragma unroll
        for (int off = 32; off >= 1; off >>= 1) v += __shfl_down(v, off);
        if (tid == 0) out[b] = v + bo[0];
    }
}

extern "C" void kernel_launch(void* const* d_in, const int* in_sizes, int n_in,
                              void* d_out, int out_size, void* d_ws, size_t ws_size,
                              hipStream_t stream) {
    const float* x   = (const float*)d_in[0];
    const float* W1x = (const float*)d_in[1];
    const float* W1h = (const float*)d_in[2];
    const float* b1  = (const float*)d_in[3];
    const float* W2x = (const float*)d_in[4];
    const float* W2h = (const float*)d_in[5];
    const float* b2  = (const float*)d_in[6];
    const float* Wo  = (const float*)d_in[7];
    const float* bo  = (const float*)d_in[8];
    float* out = (float*)d_out;

    drnn_kernel<<<NBATCH, 512, 0, stream>>>(x, W1x, W1h, b1, W2x, W2h, b2,
                                            Wo, bo, out);
}

// Round 5
// 541.211 us; speedup vs baseline: 25.9252x; 1.3733x over previous
//
#include <hip/hip_runtime.h>
#include <math.h>

#define T      512
#define NBATCH 512
#define IN_DIM 64
#define H      100
#define KCAT   208   // concatenated input: A-part [0..103] + B-part [104..207]
#define NCHUNK 52    // KCAT/4 float4 chunks
#define CPT    13    // chunks per thread (t=4 K-split)

// tanh(a) = 1 - 2/(exp(2a)+1)  -- overflow-safe at both ends.
__device__ __forceinline__ float fast_tanh(float a) {
    float e = __expf(2.0f * a);
    return 1.0f - 2.0f / (e + 1.0f);
}

// weight element for concatenated row R (A rows 0..103 pad(kvA), B rows 104..207 pad 100)
__device__ __forceinline__ float wval(const float* __restrict__ WA,
                                      const float* __restrict__ WB,
                                      int kvA, int R, int col) {
    if (R < 104) {
        int rr = (R < kvA) ? R : 0;
        float v = WA[rr * H + col];
        return (R < kvA) ? v : 0.f;
    }
    int rb = R - 104;
    int rr = (rb < H) ? rb : 0;
    float v = WB[rr * H + col];
    return (rb < H) ? v : 0.f;
}

__device__ __forceinline__ float4 wload4(const float* __restrict__ WA,
                                         const float* __restrict__ WB,
                                         int kvA, int R0, int col) {
    return make_float4(wval(WA, WB, kvA, R0 + 0, col),
                       wval(WA, WB, kvA, R0 + 1, col),
                       wval(WA, WB, kvA, R0 + 2, col),
                       wval(WA, WB, kvA, R0 + 3, col));
}

// ---------------------------------------------------------------------------
// Block = 256 threads, one batch element. Waves 0-1: layer 1; waves 2-3:
// layer 2 (pipelined one timestep behind). Within a layer-half: group
// g = idx>>2 owns neurons 4g..4g+3 (g<25 active), lane s = idx&3 owns input
// chunks {s, s+4, ..., s+48} of the 208-long concatenated contraction.
// 52 NAMED float4 weight regs per thread -> 208 FMAs per 13 LDS reads
// (ratio 4 = CU FMA:LDS balance point; R4 at ratio 1 was LDS-BW-bound).
// Partials combined with 2-step __shfl_xor butterfly; lane s finalizes
// neuron 4g+s (bias+tanh) and stores it.
// ---------------------------------------------------------------------------

#define CHUNKS(X) X(0) X(1) X(2) X(3) X(4) X(5) X(6) X(7) X(8) X(9) X(10) X(11) X(12)

#define WDECL(C) float4 wq##C##_0, wq##C##_1, wq##C##_2, wq##C##_3;

#define WLOADC(C) { const int R0_ = 16 * (C) + 4 * s;            \
    wq##C##_0 = wload4(WpA, WpB, kvA, R0_, c0);                  \
    wq##C##_1 = wload4(WpA, WpB, kvA, R0_, c1);                  \
    wq##C##_2 = wload4(WpA, WpB, kvA, R0_, c2);                  \
    wq##C##_3 = wload4(WpA, WpB, kvA, R0_, c3); }

#define STEP(C) { float4 v_ = pin_[4 * (C) + s];                                  \
    a0 = fmaf(v_.x, wq##C##_0.x, a0); a1 = fmaf(v_.x, wq##C##_1.x, a1);           \
    a2 = fmaf(v_.x, wq##C##_2.x, a2); a3 = fmaf(v_.x, wq##C##_3.x, a3);           \
    a0 = fmaf(v_.y, wq##C##_0.y, a0); a1 = fmaf(v_.y, wq##C##_1.y, a1);           \
    a2 = fmaf(v_.y, wq##C##_2.y, a2); a3 = fmaf(v_.y, wq##C##_3.y, a3);           \
    a0 = fmaf(v_.z, wq##C##_0.z, a0); a1 = fmaf(v_.z, wq##C##_1.z, a1);           \
    a2 = fmaf(v_.z, wq##C##_2.z, a2); a3 = fmaf(v_.z, wq##C##_3.z, a3);           \
    a0 = fmaf(v_.w, wq##C##_0.w, a0); a1 = fmaf(v_.w, wq##C##_1.w, a1);           \
    a2 = fmaf(v_.w, wq##C##_2.w, a2); a3 = fmaf(v_.w, wq##C##_3.w, a3); }

#define DOT(pin, hv) {                                           \
    const float4* pin_ = (pin);                                  \
    float a0 = 0.f, a1 = 0.f, a2 = 0.f, a3 = 0.f;                \
    CHUNKS(STEP)                                                 \
    a0 += __shfl_xor(a0, 1); a1 += __shfl_xor(a1, 1);            \
    a2 += __shfl_xor(a2, 1); a3 += __shfl_xor(a3, 1);            \
    a0 += __shfl_xor(a0, 2); a1 += __shfl_xor(a1, 2);            \
    a2 += __shfl_xor(a2, 2); a3 += __shfl_xor(a3, 2);            \
    float t_ = (s == 0) ? a0 : (s == 1) ? a1 : (s == 2) ? a2 : a3; \
    hv = fast_tanh(t_ + bj); }

__global__ __launch_bounds__(256, 2)
void drnn_kernel(const float* __restrict__ x,
                 const float* __restrict__ W1x, const float* __restrict__ W1h,
                 const float* __restrict__ b1,
                 const float* __restrict__ W2x, const float* __restrict__ W2h,
                 const float* __restrict__ b2,
                 const float* __restrict__ Wo,  const float* __restrict__ bo,
                 float* __restrict__ out)
{
    // in1: [x_t pad104 | h1 pad104]; in2: [h1 pad104 | h2 pad104]
    __shared__ __align__(16) float in1[2][KCAT];
    __shared__ __align__(16) float in2[2][KCAT];

    const int tid = threadIdx.x;
    const int b   = blockIdx.x;
    const float* __restrict__ xrow = x + (size_t)b * T * IN_DIM;

    // ---- zero-init LDS (pads must stay 0; h(-1)=0; h2(-1) slot stays 0) ----
    for (int k = tid; k < 2 * KCAT; k += 256) {
        (&in1[0][0])[k] = 0.f;
        (&in2[0][0])[k] = 0.f;
    }
    if (tid < IN_DIM) in1[0][tid] = xrow[tid];   // x(0)

    const bool isL1 = (tid < 128);
    const int  idx  = tid & 127;
    const int  g    = idx >> 2;          // neuron group (g<25 active)
    const int  s    = idx & 3;           // K-split lane
    const int  j    = 4 * g;
    const bool stok = (g < 25);
    const int  c0 = (j + 0 < H) ? j + 0 : H - 1;
    const int  c1 = (j + 1 < H) ? j + 1 : H - 1;
    const int  c2 = (j + 2 < H) ? j + 2 : H - 1;
    const int  c3 = (j + 3 < H) ? j + 3 : H - 1;
    const int  cs = (j + s < H) ? j + s : H - 1;   // neuron this lane finalizes

    const float* __restrict__ WpA = isL1 ? W1x : W2x;
    const float* __restrict__ WpB = isL1 ? W1h : W2h;
    const int kvA = isL1 ? IN_DIM : H;
    const float bj = (isL1 ? b1 : b2)[cs];

    // ---- 52 named float4 weight registers ----
    CHUNKS(WDECL)
    CHUNKS(WLOADC)

    // ---- even/odd-iteration pointers (wave-uniform role select) ----
    const float4* pe = (const float4*)(isL1 ? in1[0] : in2[0]);
    const float4* po = (const float4*)(isL1 ? in1[1] : in2[1]);
    float* w1a_e = &in1[1][104 + cs];   // L1 even: h1 -> own recurrent slot
    float* w1b_e = &in2[1][cs];         //          and L2's A slot
    float* w2_e  = &in2[1][104 + cs];   // L2 even: h2 recurrent slot
    float* w1a_o = &in1[0][104 + cs];
    float* w1b_o = &in2[0][cs];
    float* w2_o  = &in2[0][104 + cs];

    // ---- x register pipeline (wave 0) ----
    float xr0 = 0.f, xr1 = 0.f;
    if (tid < 64) {
        xr0 = xrow[1 * IN_DIM + tid];   // x(1)
        xr1 = xrow[2 * IN_DIM + tid];   // x(2)
    }

    __syncthreads();

    // Iter i: L1 computes h1(i); L2 computes h2(i-1).
    #pragma unroll 1
    for (int i = 0; i < T; i += 2) {
        // ---- even body (parity 0, write slot 1) ----
        {
            float hv;
            DOT(pe, hv)
            if (isL1) {
                if (stok) { *w1a_e = hv; *w1b_e = hv; }
            } else if (stok && i > 0) {
                *w2_e = hv;             // skip bogus h2(-1) at i==0
            }
            if (tid < 64) {
                in1[1][tid] = xr0;      // x(i+1)
                xr0 = xr1;
                if (i + 3 < T) xr1 = xrow[(size_t)(i + 3) * IN_DIM + tid];
            }
        }
        __syncthreads();
        // ---- odd body (parity 1, write slot 0) ----
        {
            float hv;
            DOT(po, hv)
            if (isL1) {
                if (stok) { *w1a_o = hv; *w1b_o = hv; }
            } else if (stok) {
                *w2_o = hv;
            }
            if (tid < 64) {
                in1[0][tid] = xr0;      // x(i+2)
                xr0 = xr1;
                if (i + 4 < T) xr1 = xrow[(size_t)(i + 4) * IN_DIM + tid];
            }
        }
        __syncthreads();
    }

    // ---- tail iter i=T (parity 0): only L2, computes h2(T-1) ----
    if (!isL1) {
        float hv;
        DOT(pe, hv)                     // in2[0]: h1(T-1) + h2(T-2)
        if (stok) *w2_e = hv;           // -> in2[1][104..]
    }
    __syncthreads();

    // ---- epilogue: h1(T-1) in in1[0][104..], h2(T-1) in in2[1][104..] ----
    if (tid < H)
        out[NBATCH + (size_t)b * H + tid] = in1[0][104 + tid];
    if (tid < H)
        out[NBATCH + (size_t)NBATCH * H + (size_t)b * H + tid] = in2[1][104 + tid];

    // out[b] = h2_T . Wo + bo  (wave-0 shuffle reduction)
    if (tid < 64) {
        float v = in2[1][104 + tid] * Wo[tid];
        if (tid + 64 < H) v += in2[1][104 + 64 + tid] * Wo[tid + 64];
        #pragma unroll
        for (int off = 32; off >= 1; off >>= 1) v += __shfl_down(v, off);
        if (tid == 0) out[b] = v + bo[0];
    }
}

extern "C" void kernel_launch(void* const* d_in, const int* in_sizes, int n_in,
                              void* d_out, int out_size, void* d_ws, size_t ws_size,
                              hipStream_t stream) {
    const float* x   = (const float*)d_in[0];
    const float* W1x = (const float*)d_in[1];
    const float* W1h = (const float*)d_in[2];
    const float* b1  = (const float*)d_in[3];
    const float* W2x = (const float*)d_in[4];
    const float* W2h = (const float*)d_in[5];
    const float* b2  = (const float*)d_in[6];
    const float* Wo  = (const float*)d_in[7];
    const float* bo  = (const float*)d_in[8];
    float* out = (float*)d_out;

    drnn_kernel<<<NBATCH, 256, 0, stream>>>(x, W1x, W1h, b1, W2x, W2h, b2,
                                            Wo, bo, out);
}